// Round 7
// baseline (244.653 us; speedup 1.0000x reference)
//
#include <hip/hip_runtime.h>

#define F 128
#define CAP 64    // bucket capacity per node (deg~Poisson(12), P(>64)~1e-30)
#define KC 32     // GEMM k chunk
#define LDAF 132  // fused sA leading dim (128+4): row bank-stride 4, 2-way reads (free)
#define LDW 160   // sW row: 8 chunks x 20 floats (distinct banks per g)
#define TR 64     // fallback GEMM row tile
#define LDA 36    // fallback sA leading dim

// ---------- tier A: zero cursor + dtype detect ----------
__global__ __launch_bounds__(256) void zero_kernel(
    const int* __restrict__ ei, int* __restrict__ flag,
    int* __restrict__ cursor, int N)
{
    int i = blockIdx.x * 256 + threadIdx.x;
    if (i < N) cursor[i] = 0;
    if (i == 0) {
        int or_hi = ei[1] | ei[3] | ei[5] | ei[7] | ei[9] | ei[11] | ei[13] | ei[15];
        *flag = (or_hi == 0) ? 1 : 0;
    }
}

__device__ __forceinline__ void load_edge(const int* __restrict__ ei, int is64,
                                          int E, int e, int& s, int& d)
{
    if (is64) {
        s = reinterpret_cast<const int2*>(ei)[e].x;
        d = reinterpret_cast<const int2*>(ei)[(size_t)E + e].x;
    } else {
        s = ei[e];
        d = ei[E + e];
    }
}

// ---------- tier A: fused position (2 edges/thread) + x->bf16 convert ------
// position is latency-bound (VALU 0.3%); the streaming convert hides under it.
__global__ __launch_bounds__(256) void posconv_kernel(
    const int* __restrict__ ei, const float* __restrict__ x,
    const int* __restrict__ flag_p, int* __restrict__ cursor,
    int* __restrict__ csr_src, unsigned int* __restrict__ xh,
    int E, int M)
{
    const int tid = blockIdx.x * 256 + threadIdx.x;
    const int T = gridDim.x * 256;
    const int is64 = *flag_p;

    // --- edges: 2 per thread, vector loads, 2 independent atomic chains ---
    int e0 = 2 * tid;
    if (e0 < E) {
        if (e0 + 1 < E) {
            int s0, d0, s1, d1;
            if (is64) {
                int4 sv = reinterpret_cast<const int4*>(ei)[tid];
                int4 dv = reinterpret_cast<const int4*>(ei)[(size_t)(E >> 1) + tid];
                s0 = sv.x; s1 = sv.z; d0 = dv.x; d1 = dv.z;
            } else {
                int2 sv = reinterpret_cast<const int2*>(ei)[tid];
                int2 dv = reinterpret_cast<const int2*>(ei)[(size_t)(E >> 1) + tid];
                s0 = sv.x; s1 = sv.y; d0 = dv.x; d1 = dv.y;
            }
            int slot0 = atomicAdd(&cursor[d0], 1);
            int slot1 = atomicAdd(&cursor[d1], 1);
            if (slot0 < CAP) csr_src[d0 * CAP + slot0] = s0;
            if (slot1 < CAP) csr_src[d1 * CAP + slot1] = s1;
        } else {
            int s, d;
            load_edge(ei, is64, E, e0, s, d);
            int slot = atomicAdd(&cursor[d], 1);
            if (slot < CAP) csr_src[d * CAP + slot] = s;
        }
    }

    // --- convert x (fp32) -> xh (bf16 pairs), RTNE ---
    const float2* x2 = reinterpret_cast<const float2*>(x);
    for (int j = tid; j < M; j += T) {
        float2 v = x2[j];
        unsigned ux = __float_as_uint(v.x);
        unsigned uy = __float_as_uint(v.y);
        unsigned lo = (ux + 0x7fffu + ((ux >> 16) & 1u)) >> 16;
        unsigned hi = (uy + 0x7fffu + ((uy >> 16) & 1u)) >> 16;
        xh[j] = lo | (hi << 16);
    }
}

__device__ __forceinline__ float4 bf16x4_to_f4(uint2 u)
{
    float4 f;
    f.x = __uint_as_float(u.x << 16);
    f.y = __uint_as_float(u.x & 0xffff0000u);
    f.z = __uint_as_float(u.y << 16);
    f.w = __uint_as_float(u.y & 0xffff0000u);
    return f;
}

// ---------- tier A: fused gather(bf16, bucket) + GEMM ----------
// Block owns 64 output rows: 4 waves gather 16 nodes each straight into LDS
// (no global agg round-trip), then the block GEMMs its LDS A-tile.
__global__ __launch_bounds__(256) void gather_gemm_kernel(
    const unsigned int* __restrict__ xh, const int* __restrict__ ei,
    const int* __restrict__ flag_p, const int* __restrict__ cursor,
    const int* __restrict__ csr_src, const float* __restrict__ W,
    const float* __restrict__ bias, float* __restrict__ out, int N, int E)
{
    __shared__ float sA[64 * LDAF];  // 33792 B
    __shared__ float sW[KC * LDW];   // 20480 B
    const int t = threadIdx.x;
    const int row0 = blockIdx.x * 64;
    const int w = t >> 6;
    const int lane = t & 63;
    const int half = lane >> 5;
    const int col = lane & 31;       // uint2 column: feats 4c..4c+3

    const uint2* x2 = reinterpret_cast<const uint2*>(xh);

    // ---- gather phase: wave w fills sA rows w*16 .. w*16+15 ----
    for (int j = 0; j < 16; ++j) {
        int lrow = w * 16 + j;
        int node = row0 + lrow;
        float4 a0 = make_float4(0.f, 0.f, 0.f, 0.f);
        float4 a1 = make_float4(0.f, 0.f, 0.f, 0.f);
        if (node < N) {
            int deg = cursor[node];
            if (deg <= CAP) {
                int sv = (lane < deg) ? csr_src[node * CAP + lane] : 0;
                int i = 0;
                for (; i + 3 < deg; i += 4) {
                    int e0 = __shfl(sv, i + half);
                    int e1 = __shfl(sv, i + 2 + half);
                    float4 v0 = bf16x4_to_f4(x2[(size_t)e0 * 32 + col]);
                    float4 v1 = bf16x4_to_f4(x2[(size_t)e1 * 32 + col]);
                    a0.x += v0.x; a0.y += v0.y; a0.z += v0.z; a0.w += v0.w;
                    a1.x += v1.x; a1.y += v1.y; a1.z += v1.z; a1.w += v1.w;
                }
                for (; i + 1 < deg; i += 2) {
                    int e0 = __shfl(sv, i + half);
                    float4 v0 = bf16x4_to_f4(x2[(size_t)e0 * 32 + col]);
                    a0.x += v0.x; a0.y += v0.y; a0.z += v0.z; a0.w += v0.w;
                }
                if (i < deg) {
                    int e0 = __shfl(sv, i);
                    if (half == 0) {
                        float4 v = bf16x4_to_f4(x2[(size_t)e0 * 32 + col]);
                        a0.x += v.x; a0.y += v.y; a0.z += v.z; a0.w += v.w;
                    }
                }
            } else {
                // overflow (adversarial only): ballot-scan the full edge list
                int is64 = *flag_p;
                for (int base = 0; base < E; base += 64) {
                    int e = base + lane;
                    int s = 0, d = -1;
                    if (e < E) load_edge(ei, is64, E, e, s, d);
                    unsigned long long m = __ballot(d == node);
                    while (m) {
                        int i = __ffsll((long long)m) - 1;
                        m &= m - 1;
                        int sb = __shfl(s, i);
                        float4 v = bf16x4_to_f4(x2[(size_t)sb * 32 + col]);
                        if (half == 0) { a0.x += v.x; a0.y += v.y; a0.z += v.z; a0.w += v.w; }
                    }
                }
            }
        }
        a0.x += a1.x; a0.y += a1.y; a0.z += a1.z; a0.w += a1.w;
        a0.x += __shfl_xor(a0.x, 32);
        a0.y += __shfl_xor(a0.y, 32);
        a0.z += __shfl_xor(a0.z, 32);
        a0.w += __shfl_xor(a0.w, 32);
        if (half == 0)
            *reinterpret_cast<float4*>(&sA[lrow * LDAF + col * 4]) = a0;
    }
    __syncthreads();

    // ---- GEMM phase: out[row0..row0+63] = sA @ W + bias ----
    const int g = t & 7;             // cols g*16 .. g*16+15
    const int r = t >> 3;            // rows r*2, r*2+1
    float acc[2][16];
    #pragma unroll
    for (int i = 0; i < 2; ++i)
        #pragma unroll
        for (int j = 0; j < 16; ++j) acc[i][j] = 0.0f;

    for (int kc = 0; kc < F; kc += KC) {
        #pragma unroll
        for (int u = 0; u < 4; ++u) {
            int idx = u * 256 + t;
            int kk = idx >> 5;
            int f4 = (idx & 31) * 4;
            float4 v = *reinterpret_cast<const float4*>(W + (size_t)(kc + kk) * F + f4);
            int chunk = f4 >> 4;
            int within = f4 & 15;
            *reinterpret_cast<float4*>(&sW[kk * LDW + chunk * 20 + within]) = v;
        }
        __syncthreads();

        #pragma unroll 8
        for (int kk = 0; kk < KC; ++kk) {
            const float* wp = &sW[kk * LDW + g * 20];
            const float4 w0 = *reinterpret_cast<const float4*>(wp + 0);
            const float4 w1 = *reinterpret_cast<const float4*>(wp + 4);
            const float4 w2 = *reinterpret_cast<const float4*>(wp + 8);
            const float4 w3 = *reinterpret_cast<const float4*>(wp + 12);
            #pragma unroll
            for (int i = 0; i < 2; ++i) {
                const float xv = sA[(r * 2 + i) * LDAF + kc + kk];
                acc[i][0]  += xv * w0.x;  acc[i][1]  += xv * w0.y;
                acc[i][2]  += xv * w0.z;  acc[i][3]  += xv * w0.w;
                acc[i][4]  += xv * w1.x;  acc[i][5]  += xv * w1.y;
                acc[i][6]  += xv * w1.z;  acc[i][7]  += xv * w1.w;
                acc[i][8]  += xv * w2.x;  acc[i][9]  += xv * w2.y;
                acc[i][10] += xv * w2.z;  acc[i][11] += xv * w2.w;
                acc[i][12] += xv * w3.x;  acc[i][13] += xv * w3.y;
                acc[i][14] += xv * w3.z;  acc[i][15] += xv * w3.w;
            }
        }
        __syncthreads();
    }

    float bv[16];
    #pragma unroll
    for (int j = 0; j < 16; ++j) bv[j] = bias[g * 16 + j];
    #pragma unroll
    for (int i = 0; i < 2; ++i) {
        int row = row0 + r * 2 + i;
        if (row < N) {
            float* o = out + (size_t)row * F + g * 16;
            #pragma unroll
            for (int j4 = 0; j4 < 4; ++j4) {
                float4 v;
                v.x = acc[i][j4 * 4 + 0] + bv[j4 * 4 + 0];
                v.y = acc[i][j4 * 4 + 1] + bv[j4 * 4 + 1];
                v.z = acc[i][j4 * 4 + 2] + bv[j4 * 4 + 2];
                v.w = acc[i][j4 * 4 + 3] + bv[j4 * 4 + 3];
                *reinterpret_cast<float4*>(o + j4 * 4) = v;
            }
        }
    }
}

// ================= fallback tiers (smaller ws) =================
__global__ __launch_bounds__(256) void init_kernel(
    const int* __restrict__ ei, const float* __restrict__ x,
    int* __restrict__ flag, int* __restrict__ zero_arr,
    unsigned int* __restrict__ xh, int N, int M)
{
    int i = blockIdx.x * 256 + threadIdx.x;
    if (i < M) {
        float2 v = reinterpret_cast<const float2*>(x)[i];
        unsigned ux = __float_as_uint(v.x);
        unsigned uy = __float_as_uint(v.y);
        unsigned lo = (ux + 0x7fffu + ((ux >> 16) & 1u)) >> 16;
        unsigned hi = (uy + 0x7fffu + ((uy >> 16) & 1u)) >> 16;
        xh[i] = lo | (hi << 16);
    }
    if (i < N) zero_arr[i] = 0;
    if (i == 0) {
        int or_hi = ei[1] | ei[3] | ei[5] | ei[7] | ei[9] | ei[11] | ei[13] | ei[15];
        *flag = (or_hi == 0) ? 1 : 0;
    }
}

__global__ __launch_bounds__(256) void position_bucket_kernel(
    const int* __restrict__ ei, const int* __restrict__ flag_p,
    int* __restrict__ cursor, int* __restrict__ csr_src, int E)
{
    int e = blockIdx.x * 256 + threadIdx.x;
    if (e >= E) return;
    int s, d;
    load_edge(ei, *flag_p, E, e, s, d);
    int slot = atomicAdd(&cursor[d], 1);
    if (slot < CAP) csr_src[d * CAP + slot] = s;
}

__global__ __launch_bounds__(256) void gather_bucket_f32_kernel(
    const float* __restrict__ x, const int* __restrict__ ei,
    const int* __restrict__ flag_p, const int* __restrict__ cursor,
    const int* __restrict__ csr_src, float* __restrict__ agg, int N, int E)
{
    int node = blockIdx.x * 4 + (threadIdx.x >> 6);
    if (node >= N) return;
    int lane = threadIdx.x & 63;
    int half = lane >> 5;
    int col = lane & 31;
    int deg = cursor[node];

    const float4* x4 = reinterpret_cast<const float4*>(x);
    float4 a0 = make_float4(0.f, 0.f, 0.f, 0.f);
    float4 a1 = make_float4(0.f, 0.f, 0.f, 0.f);

    if (deg <= CAP) {
        int sv = (lane < deg) ? csr_src[node * CAP + lane] : 0;
        int i = 0;
        for (; i + 3 < deg; i += 4) {
            int e0 = __shfl(sv, i + half);
            int e1 = __shfl(sv, i + 2 + half);
            float4 v0 = x4[(size_t)e0 * 32 + col];
            float4 v1 = x4[(size_t)e1 * 32 + col];
            a0.x += v0.x; a0.y += v0.y; a0.z += v0.z; a0.w += v0.w;
            a1.x += v1.x; a1.y += v1.y; a1.z += v1.z; a1.w += v1.w;
        }
        for (; i + 1 < deg; i += 2) {
            int e0 = __shfl(sv, i + half);
            float4 v0 = x4[(size_t)e0 * 32 + col];
            a0.x += v0.x; a0.y += v0.y; a0.z += v0.z; a0.w += v0.w;
        }
        if (i < deg) {
            int e0 = __shfl(sv, i);
            if (half == 0) {
                float4 v = x4[(size_t)e0 * 32 + col];
                a0.x += v.x; a0.y += v.y; a0.z += v.z; a0.w += v.w;
            }
        }
    } else {
        int is64 = *flag_p;
        for (int base = 0; base < E; base += 64) {
            int e = base + lane;
            int s = 0, d = -1;
            if (e < E) load_edge(ei, is64, E, e, s, d);
            unsigned long long m = __ballot(d == node);
            while (m) {
                int i = __ffsll((long long)m) - 1;
                m &= m - 1;
                int sb = __shfl(s, i);
                float4 v = x4[(size_t)sb * 32 + col];
                if (half == 0) { a0.x += v.x; a0.y += v.y; a0.z += v.z; a0.w += v.w; }
            }
        }
    }
    a0.x += a1.x; a0.y += a1.y; a0.z += a1.z; a0.w += a1.w;
    a0.x += __shfl_xor(a0.x, 32);
    a0.y += __shfl_xor(a0.y, 32);
    a0.z += __shfl_xor(a0.z, 32);
    a0.w += __shfl_xor(a0.w, 32);
    if (half == 0)
        reinterpret_cast<float4*>(agg)[(size_t)node * 32 + col] = a0;
}

__global__ __launch_bounds__(256) void scatter_kernel(
    const float* __restrict__ x, const int* __restrict__ ei,
    const int* __restrict__ flag_p, float* __restrict__ agg, int E)
{
    int tid = blockIdx.x * 256 + threadIdx.x;
    int e = tid >> 5;
    if (e >= E) return;
    int c = (tid & 31) << 2;
    int s, d;
    load_edge(ei, *flag_p, E, e, s, d);
    float4 v = *reinterpret_cast<const float4*>(x + (size_t)s * F + c);
    float* o = agg + (size_t)d * F + c;
    unsafeAtomicAdd(o + 0, v.x);
    unsafeAtomicAdd(o + 1, v.y);
    unsafeAtomicAdd(o + 2, v.z);
    unsafeAtomicAdd(o + 3, v.w);
}

// in-place fallback GEMM: io = io @ W + bias
__global__ __launch_bounds__(256) void gemm_kernel(
    float* __restrict__ io, const float* __restrict__ W,
    const float* __restrict__ bias, int N)
{
    __shared__ float sA[TR * LDA];
    __shared__ float sW[KC * LDW];
    const int t = threadIdx.x;
    const int row0 = blockIdx.x * TR;
    const int g = t & 7;
    const int r = t >> 3;

    float acc[2][16];
    #pragma unroll
    for (int i = 0; i < 2; ++i)
        #pragma unroll
        for (int j = 0; j < 16; ++j) acc[i][j] = 0.0f;

    for (int kc = 0; kc < F; kc += KC) {
        #pragma unroll
        for (int u = 0; u < 2; ++u) {
            int idx = u * 256 + t;
            int row = idx >> 3;
            int k4 = (idx & 7) * 4;
            int grow = row0 + row;
            float4 v = (grow < N)
                ? *reinterpret_cast<const float4*>(io + (size_t)grow * F + kc + k4)
                : make_float4(0.f, 0.f, 0.f, 0.f);
            *reinterpret_cast<float4*>(&sA[row * LDA + k4]) = v;
        }
        #pragma unroll
        for (int u = 0; u < 4; ++u) {
            int idx = u * 256 + t;
            int kk = idx >> 5;
            int f4 = (idx & 31) * 4;
            float4 v = *reinterpret_cast<const float4*>(W + (size_t)(kc + kk) * F + f4);
            int chunk = f4 >> 4;
            int within = f4 & 15;
            *reinterpret_cast<float4*>(&sW[kk * LDW + chunk * 20 + within]) = v;
        }
        __syncthreads();

        #pragma unroll 8
        for (int kk = 0; kk < KC; ++kk) {
            const float* wp = &sW[kk * LDW + g * 20];
            const float4 w0 = *reinterpret_cast<const float4*>(wp + 0);
            const float4 w1 = *reinterpret_cast<const float4*>(wp + 4);
            const float4 w2 = *reinterpret_cast<const float4*>(wp + 8);
            const float4 w3 = *reinterpret_cast<const float4*>(wp + 12);
            #pragma unroll
            for (int i = 0; i < 2; ++i) {
                const float xv = sA[(r * 2 + i) * LDA + kk];
                acc[i][0]  += xv * w0.x;  acc[i][1]  += xv * w0.y;
                acc[i][2]  += xv * w0.z;  acc[i][3]  += xv * w0.w;
                acc[i][4]  += xv * w1.x;  acc[i][5]  += xv * w1.y;
                acc[i][6]  += xv * w1.z;  acc[i][7]  += xv * w1.w;
                acc[i][8]  += xv * w2.x;  acc[i][9]  += xv * w2.y;
                acc[i][10] += xv * w2.z;  acc[i][11] += xv * w2.w;
                acc[i][12] += xv * w3.x;  acc[i][13] += xv * w3.y;
                acc[i][14] += xv * w3.z;  acc[i][15] += xv * w3.w;
            }
        }
        __syncthreads();
    }

    float bv[16];
    #pragma unroll
    for (int j = 0; j < 16; ++j) bv[j] = bias[g * 16 + j];
    #pragma unroll
    for (int i = 0; i < 2; ++i) {
        int row = row0 + r * 2 + i;
        if (row < N) {
            float* o = io + (size_t)row * F + g * 16;
            #pragma unroll
            for (int j4 = 0; j4 < 4; ++j4) {
                float4 v;
                v.x = acc[i][j4 * 4 + 0] + bv[j4 * 4 + 0];
                v.y = acc[i][j4 * 4 + 1] + bv[j4 * 4 + 1];
                v.z = acc[i][j4 * 4 + 2] + bv[j4 * 4 + 2];
                v.w = acc[i][j4 * 4 + 3] + bv[j4 * 4 + 3];
                *reinterpret_cast<float4*>(o + j4 * 4) = v;
            }
        }
    }
}

extern "C" void kernel_launch(void* const* d_in, const int* in_sizes, int n_in,
                              void* d_out, int out_size, void* d_ws, size_t ws_size,
                              hipStream_t stream) {
    const float* x  = (const float*)d_in[0];
    const int*   ei = (const int*)d_in[1];
    const float* W2 = (const float*)d_in[5];
    const float* b2 = (const float*)d_in[6];
    float* out = (float*)d_out;

    const int N = in_sizes[0] / F;   // 50000
    const int E = in_sizes[2];       // 600000
    const int nblk = (N + 255) / 256;
    const int M = N * (F / 2);       // bf16-pair count
    const int eblk = (E + 255) / 256;

    int* ws = (int*)d_ws;
    // tier A: flag[16], cursor[N], csr_src[N*CAP], xh[M]
    size_t needA = (size_t)(16 + N + (size_t)N * CAP + M) * sizeof(int);
    // tier B: same minus xh (fp32 bucket gather + separate gemm)
    size_t needB = (size_t)(16 + N + (size_t)N * CAP) * sizeof(int);

    if (ws_size >= needA) {
        int* flag    = ws;
        int* cursor  = flag + 16;
        int* csr_src = cursor + N;
        unsigned int* xh = (unsigned int*)(csr_src + (size_t)N * CAP);

        zero_kernel<<<nblk, 256, 0, stream>>>(ei, flag, cursor, N);
        int pblk = ((E + 1) / 2 + 255) / 256;
        posconv_kernel<<<pblk, 256, 0, stream>>>(ei, x, flag, cursor, csr_src, xh, E, M);
        gather_gemm_kernel<<<(N + 63) / 64, 256, 0, stream>>>(
            xh, ei, flag, cursor, csr_src, W2, b2, out, N, E);
    } else if (ws_size >= needB) {
        int* flag    = ws;
        int* cursor  = flag + 16;
        int* csr_src = cursor + N;
        init_kernel<<<nblk, 256, 0, stream>>>(ei, x, flag, cursor, nullptr, N, 0);
        position_bucket_kernel<<<eblk, 256, 0, stream>>>(ei, flag, cursor, csr_src, E);
        gather_bucket_f32_kernel<<<(N + 3) / 4, 256, 0, stream>>>(
            x, ei, flag, cursor, csr_src, out, N, E);
        gemm_kernel<<<(N + TR - 1) / TR, 256, 0, stream>>>(out, W2, b2, N);
    } else {
        int* flag = ws;
        init_kernel<<<1, 64, 0, stream>>>(ei, x, flag, flag + 16, nullptr, 0, 0);
        hipMemsetAsync(out, 0, (size_t)N * F * sizeof(float), stream);
        scatter_kernel<<<(E * 32 + 255) / 256, 256, 0, stream>>>(x, ei, flag, out, E);
        gemm_kernel<<<(N + TR - 1) / TR, 256, 0, stream>>>(out, W2, b2, N);
    }
}

// Round 8
// 165.851 us; speedup vs baseline: 1.4751x; 1.4751x over previous
//
#include <hip/hip_runtime.h>

#define F 128
#define CAP 64    // bucket capacity per node (deg~Poisson(12), P(>64)~1e-30)
#define LDT 136   // sWt leading dim (bf16 elems): 16B-aligned rows
#define TR 64     // fallback GEMM row tile
#define KC 32
#define LDA 36
#define LDW 160

typedef __attribute__((ext_vector_type(8))) short bf16x8;
typedef __attribute__((ext_vector_type(4))) float f32x4;

__device__ __forceinline__ unsigned short bf16r(float f)
{
    unsigned u = __float_as_uint(f);
    return (unsigned short)((u + 0x7fffu + ((u >> 16) & 1u)) >> 16);
}

// ---------- zero cursor + dtype detect ----------
__global__ __launch_bounds__(256) void zero_kernel(
    const int* __restrict__ ei, int* __restrict__ flag,
    int* __restrict__ cursor, int N)
{
    int i = blockIdx.x * 256 + threadIdx.x;
    if (i < N) cursor[i] = 0;
    if (i == 0) {
        int or_hi = ei[1] | ei[3] | ei[5] | ei[7] | ei[9] | ei[11] | ei[13] | ei[15];
        *flag = (or_hi == 0) ? 1 : 0;
    }
}

__device__ __forceinline__ void load_edge(const int* __restrict__ ei, int is64,
                                          int E, int e, int& s, int& d)
{
    if (is64) {
        s = reinterpret_cast<const int2*>(ei)[e].x;
        d = reinterpret_cast<const int2*>(ei)[(size_t)E + e].x;
    } else {
        s = ei[e];
        d = ei[E + e];
    }
}

// ---------- fused: position (1 edge/thread) + x->bf16 + W->Wt bf16 ----------
// position is latency-bound (VALU 0.3%); the streaming converts hide under it.
__global__ __launch_bounds__(256) void posconv_kernel(
    const int* __restrict__ ei, const float* __restrict__ x,
    const float* __restrict__ W, const int* __restrict__ flag_p,
    int* __restrict__ cursor, int* __restrict__ csr_src,
    unsigned int* __restrict__ xh, unsigned short* __restrict__ Wt,
    int E, int M)
{
    const int tid = blockIdx.x * 256 + threadIdx.x;
    const int T = gridDim.x * 256;
    const int is64 = *flag_p;

    // --- edge slot-assign (atomic latency dominates; rest overlaps) ---
    if (tid < E) {
        int s, d;
        load_edge(ei, is64, E, tid, s, d);
        int slot = atomicAdd(&cursor[d], 1);
        if (slot < CAP) csr_src[d * CAP + slot] = s;
    }

    // --- x (fp32) -> xh (bf16 pairs), RTNE ---
    const float2* x2 = reinterpret_cast<const float2*>(x);
    for (int j = tid; j < M; j += T) {
        float2 v = x2[j];
        xh[j] = (unsigned)bf16r(v.x) | ((unsigned)bf16r(v.y) << 16);
    }

    // --- W (fp32, [k][n]) -> Wt (bf16, [n][k]) ---
    for (int j = tid; j < F * F; j += T) {
        int k = j >> 7, n = j & 127;
        Wt[n * F + k] = bf16r(W[j]);
    }
}

__device__ __forceinline__ float4 bf16x4_to_f4(uint2 u)
{
    float4 f;
    f.x = __uint_as_float(u.x << 16);
    f.y = __uint_as_float(u.x & 0xffff0000u);
    f.z = __uint_as_float(u.y << 16);
    f.w = __uint_as_float(u.y & 0xffff0000u);
    return f;
}

// ---------- bucket gather (bf16 in, bf16 agg out): one node per wave ----------
__global__ __launch_bounds__(256) void gather_bucket_kernel(
    const unsigned int* __restrict__ xh, const int* __restrict__ ei,
    const int* __restrict__ flag_p, const int* __restrict__ cursor,
    const int* __restrict__ csr_src, unsigned int* __restrict__ aggbf,
    int N, int E)
{
    int node = blockIdx.x * 4 + (threadIdx.x >> 6);
    if (node >= N) return;
    int lane = threadIdx.x & 63;
    int half = lane >> 5;
    int col = lane & 31;              // uint2 column: feats 4c..4c+3
    int deg = cursor[node];

    const uint2* x2 = reinterpret_cast<const uint2*>(xh);
    float4 a0 = make_float4(0.f, 0.f, 0.f, 0.f);
    float4 a1 = make_float4(0.f, 0.f, 0.f, 0.f);

    if (deg <= CAP) {
        int sv = (lane < deg) ? csr_src[node * CAP + lane] : 0;
        int i = 0;
        for (; i + 3 < deg; i += 4) {
            int e0 = __shfl(sv, i + half);
            int e1 = __shfl(sv, i + 2 + half);
            float4 v0 = bf16x4_to_f4(x2[(size_t)e0 * 32 + col]);
            float4 v1 = bf16x4_to_f4(x2[(size_t)e1 * 32 + col]);
            a0.x += v0.x; a0.y += v0.y; a0.z += v0.z; a0.w += v0.w;
            a1.x += v1.x; a1.y += v1.y; a1.z += v1.z; a1.w += v1.w;
        }
        for (; i + 1 < deg; i += 2) {
            int e0 = __shfl(sv, i + half);
            float4 v0 = bf16x4_to_f4(x2[(size_t)e0 * 32 + col]);
            a0.x += v0.x; a0.y += v0.y; a0.z += v0.z; a0.w += v0.w;
        }
        if (i < deg) {
            int e0 = __shfl(sv, i);
            if (half == 0) {
                float4 v = bf16x4_to_f4(x2[(size_t)e0 * 32 + col]);
                a0.x += v.x; a0.y += v.y; a0.z += v.z; a0.w += v.w;
            }
        }
    } else {
        // overflow (adversarial only): ballot-scan the full edge list
        int is64 = *flag_p;
        for (int base = 0; base < E; base += 64) {
            int e = base + lane;
            int s = 0, d = -1;
            if (e < E) load_edge(ei, is64, E, e, s, d);
            unsigned long long m = __ballot(d == node);
            while (m) {
                int i = __ffsll((long long)m) - 1;
                m &= m - 1;
                int sb = __shfl(s, i);
                float4 v = bf16x4_to_f4(x2[(size_t)sb * 32 + col]);
                if (half == 0) { a0.x += v.x; a0.y += v.y; a0.z += v.z; a0.w += v.w; }
            }
        }
    }
    a0.x += a1.x; a0.y += a1.y; a0.z += a1.z; a0.w += a1.w;
    a0.x += __shfl_xor(a0.x, 32);
    a0.y += __shfl_xor(a0.y, 32);
    a0.z += __shfl_xor(a0.z, 32);
    a0.w += __shfl_xor(a0.w, 32);
    if (half == 0) {
        uint2 o;
        o.x = (unsigned)bf16r(a0.x) | ((unsigned)bf16r(a0.y) << 16);
        o.y = (unsigned)bf16r(a0.z) | ((unsigned)bf16r(a0.w) << 16);
        reinterpret_cast<uint2*>(aggbf)[(size_t)node * 32 + col] = o;
    }
}

// ---------- MFMA GEMM: out[N,128] = aggbf(bf16) @ W + bias (fp32 acc) -------
// Block = 256 thr = 4 waves; wave owns 16 rows x 128 cols (8 16x16 tiles).
// A-frag: A[m=lane&15][k=quad*8+j]; B-frag from LDS Wt[n][k]; C/D:
// col=lane&15, row=quad*4+reg  (m89/m91-verified mappings).
__global__ __launch_bounds__(256) void gemm_mfma_kernel(
    const unsigned short* __restrict__ aggbf, const unsigned short* __restrict__ Wt,
    const float* __restrict__ bias, float* __restrict__ out, int N)
{
    __shared__ unsigned short sWt[F * LDT];   // 34816 B
    const int t = threadIdx.x;

    // stage Wt: 2048 uint4, contiguous global, padded LDS rows
    const uint4* Wg = reinterpret_cast<const uint4*>(Wt);
    #pragma unroll
    for (int u = 0; u < 8; ++u) {
        int idx = u * 256 + t;       // 0..2047
        int n = idx >> 4;
        int c = idx & 15;
        *reinterpret_cast<uint4*>(&sWt[n * LDT + c * 8]) = Wg[idx];
    }
    __syncthreads();

    const int wv = t >> 6, lane = t & 63;
    const int quad = lane >> 4, n15 = lane & 15;
    const int rbase = blockIdx.x * 64 + wv * 16;

    f32x4 acc[8];
    #pragma unroll
    for (int i = 0; i < 8; ++i) acc[i] = (f32x4){0.f, 0.f, 0.f, 0.f};

    const int arow = rbase + n15;
    const bool aval = (arow < N);
    #pragma unroll
    for (int kc = 0; kc < F; kc += 32) {
        bf16x8 af;
        if (aval)
            af = *reinterpret_cast<const bf16x8*>(aggbf + (size_t)arow * F + kc + quad * 8);
        else
            af = (bf16x8){0, 0, 0, 0, 0, 0, 0, 0};
        #pragma unroll
        for (int nt = 0; nt < 8; ++nt) {
            bf16x8 bfr = *reinterpret_cast<const bf16x8*>(
                &sWt[(nt * 16 + n15) * LDT + kc + quad * 8]);
            acc[nt] = __builtin_amdgcn_mfma_f32_16x16x32_bf16(af, bfr, acc[nt], 0, 0, 0);
        }
    }

    #pragma unroll
    for (int nt = 0; nt < 8; ++nt) {
        float bv = bias[nt * 16 + n15];
        #pragma unroll
        for (int reg = 0; reg < 4; ++reg) {
            int row = rbase + quad * 4 + reg;
            if (row < N)
                out[(size_t)row * F + nt * 16 + n15] = acc[nt][reg] + bv;
        }
    }
}

// ================= fallback tiers (smaller ws) =================
__global__ __launch_bounds__(256) void init_kernel(
    const int* __restrict__ ei, int* __restrict__ flag,
    int* __restrict__ zero_arr, int N)
{
    int i = blockIdx.x * 256 + threadIdx.x;
    if (i < N) zero_arr[i] = 0;
    if (i == 0) {
        int or_hi = ei[1] | ei[3] | ei[5] | ei[7] | ei[9] | ei[11] | ei[13] | ei[15];
        *flag = (or_hi == 0) ? 1 : 0;
    }
}

__global__ __launch_bounds__(256) void position_bucket_kernel(
    const int* __restrict__ ei, const int* __restrict__ flag_p,
    int* __restrict__ cursor, int* __restrict__ csr_src, int E)
{
    int e = blockIdx.x * 256 + threadIdx.x;
    if (e >= E) return;
    int s, d;
    load_edge(ei, *flag_p, E, e, s, d);
    int slot = atomicAdd(&cursor[d], 1);
    if (slot < CAP) csr_src[d * CAP + slot] = s;
}

__global__ __launch_bounds__(256) void gather_bucket_f32_kernel(
    const float* __restrict__ x, const int* __restrict__ ei,
    const int* __restrict__ flag_p, const int* __restrict__ cursor,
    const int* __restrict__ csr_src, float* __restrict__ agg, int N, int E)
{
    int node = blockIdx.x * 4 + (threadIdx.x >> 6);
    if (node >= N) return;
    int lane = threadIdx.x & 63;
    int half = lane >> 5;
    int col = lane & 31;
    int deg = cursor[node];

    const float4* x4 = reinterpret_cast<const float4*>(x);
    float4 a0 = make_float4(0.f, 0.f, 0.f, 0.f);
    float4 a1 = make_float4(0.f, 0.f, 0.f, 0.f);

    if (deg <= CAP) {
        int sv = (lane < deg) ? csr_src[node * CAP + lane] : 0;
        int i = 0;
        for (; i + 3 < deg; i += 4) {
            int e0 = __shfl(sv, i + half);
            int e1 = __shfl(sv, i + 2 + half);
            float4 v0 = x4[(size_t)e0 * 32 + col];
            float4 v1 = x4[(size_t)e1 * 32 + col];
            a0.x += v0.x; a0.y += v0.y; a0.z += v0.z; a0.w += v0.w;
            a1.x += v1.x; a1.y += v1.y; a1.z += v1.z; a1.w += v1.w;
        }
        for (; i + 1 < deg; i += 2) {
            int e0 = __shfl(sv, i + half);
            float4 v0 = x4[(size_t)e0 * 32 + col];
            a0.x += v0.x; a0.y += v0.y; a0.z += v0.z; a0.w += v0.w;
        }
        if (i < deg) {
            int e0 = __shfl(sv, i);
            if (half == 0) {
                float4 v = x4[(size_t)e0 * 32 + col];
                a0.x += v.x; a0.y += v.y; a0.z += v.z; a0.w += v.w;
            }
        }
    } else {
        int is64 = *flag_p;
        for (int base = 0; base < E; base += 64) {
            int e = base + lane;
            int s = 0, d = -1;
            if (e < E) load_edge(ei, is64, E, e, s, d);
            unsigned long long m = __ballot(d == node);
            while (m) {
                int i = __ffsll((long long)m) - 1;
                m &= m - 1;
                int sb = __shfl(s, i);
                float4 v = x4[(size_t)sb * 32 + col];
                if (half == 0) { a0.x += v.x; a0.y += v.y; a0.z += v.z; a0.w += v.w; }
            }
        }
    }
    a0.x += a1.x; a0.y += a1.y; a0.z += a1.z; a0.w += a1.w;
    a0.x += __shfl_xor(a0.x, 32);
    a0.y += __shfl_xor(a0.y, 32);
    a0.z += __shfl_xor(a0.z, 32);
    a0.w += __shfl_xor(a0.w, 32);
    if (half == 0)
        reinterpret_cast<float4*>(agg)[(size_t)node * 32 + col] = a0;
}

__global__ __launch_bounds__(256) void scatter_kernel(
    const float* __restrict__ x, const int* __restrict__ ei,
    const int* __restrict__ flag_p, float* __restrict__ agg, int E)
{
    int tid = blockIdx.x * 256 + threadIdx.x;
    int e = tid >> 5;
    if (e >= E) return;
    int c = (tid & 31) << 2;
    int s, d;
    load_edge(ei, *flag_p, E, e, s, d);
    float4 v = *reinterpret_cast<const float4*>(x + (size_t)s * F + c);
    float* o = agg + (size_t)d * F + c;
    unsafeAtomicAdd(o + 0, v.x);
    unsafeAtomicAdd(o + 1, v.y);
    unsafeAtomicAdd(o + 2, v.z);
    unsafeAtomicAdd(o + 3, v.w);
}

// in-place fallback VALU GEMM: io = io @ W + bias
__global__ __launch_bounds__(256) void gemm_kernel(
    float* __restrict__ io, const float* __restrict__ W,
    const float* __restrict__ bias, int N)
{
    __shared__ float sA[TR * LDA];
    __shared__ float sW[KC * LDW];
    const int t = threadIdx.x;
    const int row0 = blockIdx.x * TR;
    const int g = t & 7;
    const int r = t >> 3;

    float acc[2][16];
    #pragma unroll
    for (int i = 0; i < 2; ++i)
        #pragma unroll
        for (int j = 0; j < 16; ++j) acc[i][j] = 0.0f;

    for (int kc = 0; kc < F; kc += KC) {
        #pragma unroll
        for (int u = 0; u < 2; ++u) {
            int idx = u * 256 + t;
            int row = idx >> 3;
            int k4 = (idx & 7) * 4;
            int grow = row0 + row;
            float4 v = (grow < N)
                ? *reinterpret_cast<const float4*>(io + (size_t)grow * F + kc + k4)
                : make_float4(0.f, 0.f, 0.f, 0.f);
            *reinterpret_cast<float4*>(&sA[row * LDA + k4]) = v;
        }
        #pragma unroll
        for (int u = 0; u < 4; ++u) {
            int idx = u * 256 + t;
            int kk = idx >> 5;
            int f4 = (idx & 31) * 4;
            float4 v = *reinterpret_cast<const float4*>(W + (size_t)(kc + kk) * F + f4);
            int chunk = f4 >> 4;
            int within = f4 & 15;
            *reinterpret_cast<float4*>(&sW[kk * LDW + chunk * 20 + within]) = v;
        }
        __syncthreads();

        #pragma unroll 8
        for (int kk = 0; kk < KC; ++kk) {
            const float* wp = &sW[kk * LDW + g * 20];
            const float4 w0 = *reinterpret_cast<const float4*>(wp + 0);
            const float4 w1 = *reinterpret_cast<const float4*>(wp + 4);
            const float4 w2 = *reinterpret_cast<const float4*>(wp + 8);
            const float4 w3 = *reinterpret_cast<const float4*>(wp + 12);
            #pragma unroll
            for (int i = 0; i < 2; ++i) {
                const float xv = sA[(r * 2 + i) * LDA + kk];
                acc[i][0]  += xv * w0.x;  acc[i][1]  += xv * w0.y;
                acc[i][2]  += xv * w0.z;  acc[i][3]  += xv * w0.w;
                acc[i][4]  += xv * w1.x;  acc[i][5]  += xv * w1.y;
                acc[i][6]  += xv * w1.z;  acc[i][7]  += xv * w1.w;
                acc[i][8]  += xv * w2.x;  acc[i][9]  += xv * w2.y;
                acc[i][10] += xv * w2.z;  acc[i][11] += xv * w2.w;
                acc[i][12] += xv * w3.x;  acc[i][13] += xv * w3.y;
                acc[i][14] += xv * w3.z;  acc[i][15] += xv * w3.w;
            }
        }
        __syncthreads();
    }

    float bv[16];
    #pragma unroll
    for (int j = 0; j < 16; ++j) bv[j] = bias[g * 16 + j];
    #pragma unroll
    for (int i = 0; i < 2; ++i) {
        int row = row0 + r * 2 + i;
        if (row < N) {
            float* o = io + (size_t)row * F + g * 16;
            #pragma unroll
            for (int j4 = 0; j4 < 4; ++j4) {
                float4 v;
                v.x = acc[i][j4 * 4 + 0] + bv[j4 * 4 + 0];
                v.y = acc[i][j4 * 4 + 1] + bv[j4 * 4 + 1];
                v.z = acc[i][j4 * 4 + 2] + bv[j4 * 4 + 2];
                v.w = acc[i][j4 * 4 + 3] + bv[j4 * 4 + 3];
                *reinterpret_cast<float4*>(o + j4 * 4) = v;
            }
        }
    }
}

extern "C" void kernel_launch(void* const* d_in, const int* in_sizes, int n_in,
                              void* d_out, int out_size, void* d_ws, size_t ws_size,
                              hipStream_t stream) {
    const float* x  = (const float*)d_in[0];
    const int*   ei = (const int*)d_in[1];
    const float* W2 = (const float*)d_in[5];
    const float* b2 = (const float*)d_in[6];
    float* out = (float*)d_out;

    const int N = in_sizes[0] / F;   // 50000
    const int E = in_sizes[2];       // 600000
    const int nblk = (N + 255) / 256;
    const int M = N * (F / 2);       // bf16-pair count for x
    const int eblk = (E + 255) / 256;

    int* ws = (int*)d_ws;
    // tier A: flag[16], cursor[N], csr_src[N*CAP], xh[M], Wt[F*F/2], aggbf[N*F/2]
    size_t needA = (size_t)(16 + N + (size_t)N * CAP + M + (F * F / 2) + (size_t)N * (F / 2))
                   * sizeof(int);
    // tier B: flag[16], cursor[N], csr_src[N*CAP]
    size_t needB = (size_t)(16 + N + (size_t)N * CAP) * sizeof(int);

    if (ws_size >= needA) {
        int* flag    = ws;
        int* cursor  = flag + 16;
        int* csr_src = cursor + N;
        unsigned int*   xh    = (unsigned int*)(csr_src + (size_t)N * CAP);
        unsigned short* Wt    = (unsigned short*)(xh + M);
        unsigned int*   aggbf = (unsigned int*)(Wt + F * F);

        zero_kernel<<<nblk, 256, 0, stream>>>(ei, flag, cursor, N);
        posconv_kernel<<<eblk, 256, 0, stream>>>(ei, x, W2, flag, cursor, csr_src,
                                                 xh, Wt, E, M);
        gather_bucket_kernel<<<(N + 3) / 4, 256, 0, stream>>>(
            xh, ei, flag, cursor, csr_src, aggbf, N, E);
        gemm_mfma_kernel<<<(N + 63) / 64, 256, 0, stream>>>(
            (const unsigned short*)aggbf, Wt, b2, out, N);
    } else if (ws_size >= needB) {
        int* flag    = ws;
        int* cursor  = flag + 16;
        int* csr_src = cursor + N;
        init_kernel<<<nblk, 256, 0, stream>>>(ei, flag, cursor, N);
        position_bucket_kernel<<<eblk, 256, 0, stream>>>(ei, flag, cursor, csr_src, E);
        gather_bucket_f32_kernel<<<(N + 3) / 4, 256, 0, stream>>>(
            x, ei, flag, cursor, csr_src, out, N, E);
        gemm_kernel<<<(N + TR - 1) / TR, 256, 0, stream>>>(out, W2, b2, N);
    } else {
        int* flag = ws;
        init_kernel<<<1, 64, 0, stream>>>(ei, flag, flag + 16, 0);
        hipMemsetAsync(out, 0, (size_t)N * F * sizeof(float), stream);
        scatter_kernel<<<(E * 32 + 255) / 256, 256, 0, stream>>>(x, ei, flag, out, E);
        gemm_kernel<<<(N + TR - 1) / TR, 256, 0, stream>>>(out, W2, b2, N);
    }
}

// Round 9
// 161.414 us; speedup vs baseline: 1.5157x; 1.0275x over previous
//
#include <hip/hip_runtime.h>

#define F 128
#define CAP 64    // bucket capacity per node (deg~Poisson(12), P(>64)~1e-30)
#define LDT 136   // sWt leading dim (bf16 elems)
#define TR 64     // fallback GEMM row tile
#define KC 32
#define LDA 36
#define LDW 160

typedef __attribute__((ext_vector_type(8))) short bf16x8;
typedef __attribute__((ext_vector_type(4))) float f32x4;

__device__ __forceinline__ unsigned short bf16r(float f)
{
    unsigned u = __float_as_uint(f);
    return (unsigned short)((u + 0x7fffu + ((u >> 16) & 1u)) >> 16);
}

__device__ __forceinline__ void load_edge(const int* __restrict__ ei, int is64,
                                          int E, int e, int& s, int& d)
{
    if (is64) {
        s = reinterpret_cast<const int2*>(ei)[e].x;
        d = reinterpret_cast<const int2*>(ei)[(size_t)E + e].x;
    } else {
        s = ei[e];
        d = ei[E + e];
    }
}

// ---------- tier A prep: zero cursor + dtype detect + x->bf16 + W->Wt ----------
__global__ __launch_bounds__(256) void prep_kernel(
    const int* __restrict__ ei, const float* __restrict__ x,
    const float* __restrict__ W, int* __restrict__ flag,
    int* __restrict__ cursor, unsigned int* __restrict__ xh,
    unsigned short* __restrict__ Wt, int N, int M)
{
    int i = blockIdx.x * 256 + threadIdx.x;
    if (i < M) {
        float2 v = reinterpret_cast<const float2*>(x)[i];
        xh[i] = (unsigned)bf16r(v.x) | ((unsigned)bf16r(v.y) << 16);
    }
    if (i < N) cursor[i] = 0;
    if (i < F * F) {
        int k = i >> 7, n = i & 127;
        Wt[n * F + k] = bf16r(W[i]);
    }
    if (i == 0) {
        int or_hi = ei[1] | ei[3] | ei[5] | ei[7] | ei[9] | ei[11] | ei[13] | ei[15];
        *flag = (or_hi == 0) ? 1 : 0;
    }
}

// ---------- tier A position: 4 edges/thread, 4 independent atomic chains,
// ushort bucket entries (requires N <= 65536) ----------
__global__ __launch_bounds__(256) void position4_kernel(
    const int* __restrict__ ei, const int* __restrict__ flag_p,
    int* __restrict__ cursor, unsigned short* __restrict__ csr16, int E)
{
    const int tid = blockIdx.x * 256 + threadIdx.x;
    const int base = 4 * tid;
    if (base >= E) return;
    const int is64 = *flag_p;

    int s[4], d[4];
    int cnt;
    if (base + 3 < E && (E & 3) == 0) {
        cnt = 4;
        if (is64) {
            // int64: element e = int2 at index e; 2 elements per int4
            const int4* sp = reinterpret_cast<const int4*>(ei);
            int4 a = sp[tid * 2], b = sp[tid * 2 + 1];
            s[0] = a.x; s[1] = a.z; s[2] = b.x; s[3] = b.z;
            const int4* dp = reinterpret_cast<const int4*>(ei) + ((size_t)E >> 1);
            int4 c = dp[tid * 2], e4 = dp[tid * 2 + 1];
            d[0] = c.x; d[1] = c.z; d[2] = e4.x; d[3] = e4.z;
        } else {
            int4 sv = reinterpret_cast<const int4*>(ei)[tid];
            int4 dv = reinterpret_cast<const int4*>(ei + E)[tid];
            s[0] = sv.x; s[1] = sv.y; s[2] = sv.z; s[3] = sv.w;
            d[0] = dv.x; d[1] = dv.y; d[2] = dv.z; d[3] = dv.w;
        }
    } else {
        cnt = E - base; if (cnt > 4) cnt = 4;
        for (int j = 0; j < cnt; ++j) load_edge(ei, is64, E, base + j, s[j], d[j]);
        for (int j = cnt; j < 4; ++j) { s[j] = 0; d[j] = 0; }
    }

    int slot[4];
    #pragma unroll
    for (int j = 0; j < 4; ++j)
        slot[j] = (j < cnt) ? atomicAdd(&cursor[d[j]], 1) : CAP;
    #pragma unroll
    for (int j = 0; j < 4; ++j)
        if (slot[j] < CAP) csr16[(size_t)d[j] * CAP + slot[j]] = (unsigned short)s[j];
}

__device__ __forceinline__ float4 bf16x4_to_f4(uint2 u)
{
    float4 f;
    f.x = __uint_as_float(u.x << 16);
    f.y = __uint_as_float(u.x & 0xffff0000u);
    f.z = __uint_as_float(u.y << 16);
    f.w = __uint_as_float(u.y & 0xffff0000u);
    return f;
}

// ---------- tier A gather (bf16 in, bf16 agg out): one node per wave ----------
__global__ __launch_bounds__(256) void gather_bucket_kernel(
    const unsigned int* __restrict__ xh, const int* __restrict__ ei,
    const int* __restrict__ flag_p, const int* __restrict__ cursor,
    const unsigned short* __restrict__ csr16, unsigned int* __restrict__ aggbf,
    int N, int E)
{
    int node = blockIdx.x * 4 + (threadIdx.x >> 6);
    if (node >= N) return;
    int lane = threadIdx.x & 63;
    int half = lane >> 5;
    int col = lane & 31;              // uint2 column: feats 4c..4c+3
    int deg = cursor[node];

    const uint2* x2 = reinterpret_cast<const uint2*>(xh);
    float4 a0 = make_float4(0.f, 0.f, 0.f, 0.f);
    float4 a1 = make_float4(0.f, 0.f, 0.f, 0.f);

    if (deg <= CAP) {
        int sv = (lane < deg) ? (int)csr16[(size_t)node * CAP + lane] : 0;
        int i = 0;
        for (; i + 3 < deg; i += 4) {
            int e0 = __shfl(sv, i + half);
            int e1 = __shfl(sv, i + 2 + half);
            float4 v0 = bf16x4_to_f4(x2[(size_t)e0 * 32 + col]);
            float4 v1 = bf16x4_to_f4(x2[(size_t)e1 * 32 + col]);
            a0.x += v0.x; a0.y += v0.y; a0.z += v0.z; a0.w += v0.w;
            a1.x += v1.x; a1.y += v1.y; a1.z += v1.z; a1.w += v1.w;
        }
        for (; i + 1 < deg; i += 2) {
            int e0 = __shfl(sv, i + half);
            float4 v0 = bf16x4_to_f4(x2[(size_t)e0 * 32 + col]);
            a0.x += v0.x; a0.y += v0.y; a0.z += v0.z; a0.w += v0.w;
        }
        if (i < deg) {
            int e0 = __shfl(sv, i);
            if (half == 0) {
                float4 v = bf16x4_to_f4(x2[(size_t)e0 * 32 + col]);
                a0.x += v.x; a0.y += v.y; a0.z += v.z; a0.w += v.w;
            }
        }
    } else {
        // overflow (adversarial only): ballot-scan the full edge list
        int is64 = *flag_p;
        for (int base = 0; base < E; base += 64) {
            int e = base + lane;
            int s = 0, d = -1;
            if (e < E) load_edge(ei, is64, E, e, s, d);
            unsigned long long m = __ballot(d == node);
            while (m) {
                int i = __ffsll((long long)m) - 1;
                m &= m - 1;
                int sb = __shfl(s, i);
                float4 v = bf16x4_to_f4(x2[(size_t)sb * 32 + col]);
                if (half == 0) { a0.x += v.x; a0.y += v.y; a0.z += v.z; a0.w += v.w; }
            }
        }
    }
    a0.x += a1.x; a0.y += a1.y; a0.z += a1.z; a0.w += a1.w;
    a0.x += __shfl_xor(a0.x, 32);
    a0.y += __shfl_xor(a0.y, 32);
    a0.z += __shfl_xor(a0.z, 32);
    a0.w += __shfl_xor(a0.w, 32);
    if (half == 0) {
        uint2 o;
        o.x = (unsigned)bf16r(a0.x) | ((unsigned)bf16r(a0.y) << 16);
        o.y = (unsigned)bf16r(a0.z) | ((unsigned)bf16r(a0.w) << 16);
        reinterpret_cast<uint2*>(aggbf)[(size_t)node * 32 + col] = o;
    }
}

// ---------- MFMA GEMM: out[N,128] = aggbf(bf16) @ W + bias (fp32 acc) -------
__global__ __launch_bounds__(256) void gemm_mfma_kernel(
    const unsigned short* __restrict__ aggbf, const unsigned short* __restrict__ Wt,
    const float* __restrict__ bias, float* __restrict__ out, int N)
{
    __shared__ unsigned short sWt[F * LDT];   // 34816 B
    const int t = threadIdx.x;

    const uint4* Wg = reinterpret_cast<const uint4*>(Wt);
    #pragma unroll
    for (int u = 0; u < 8; ++u) {
        int idx = u * 256 + t;       // 0..2047
        int n = idx >> 4;
        int c = idx & 15;
        *reinterpret_cast<uint4*>(&sWt[n * LDT + c * 8]) = Wg[idx];
    }
    __syncthreads();

    const int wv = t >> 6, lane = t & 63;
    const int quad = lane >> 4, n15 = lane & 15;
    const int rbase = blockIdx.x * 64 + wv * 16;

    f32x4 acc[8];
    #pragma unroll
    for (int i = 0; i < 8; ++i) acc[i] = (f32x4){0.f, 0.f, 0.f, 0.f};

    const int arow = rbase + n15;
    const bool aval = (arow < N);
    #pragma unroll
    for (int kc = 0; kc < F; kc += 32) {
        bf16x8 af;
        if (aval)
            af = *reinterpret_cast<const bf16x8*>(aggbf + (size_t)arow * F + kc + quad * 8);
        else
            af = (bf16x8){0, 0, 0, 0, 0, 0, 0, 0};
        #pragma unroll
        for (int nt = 0; nt < 8; ++nt) {
            bf16x8 bfr = *reinterpret_cast<const bf16x8*>(
                &sWt[(nt * 16 + n15) * LDT + kc + quad * 8]);
            acc[nt] = __builtin_amdgcn_mfma_f32_16x16x32_bf16(af, bfr, acc[nt], 0, 0, 0);
        }
    }

    #pragma unroll
    for (int nt = 0; nt < 8; ++nt) {
        float bv = bias[nt * 16 + n15];
        #pragma unroll
        for (int reg = 0; reg < 4; ++reg) {
            int row = rbase + quad * 4 + reg;
            if (row < N)
                out[(size_t)row * F + nt * 16 + n15] = acc[nt][reg] + bv;
        }
    }
}

// ================= fallback tiers (smaller ws or huge N) =================
__global__ __launch_bounds__(256) void init_kernel(
    const int* __restrict__ ei, int* __restrict__ flag,
    int* __restrict__ zero_arr, int N)
{
    int i = blockIdx.x * 256 + threadIdx.x;
    if (i < N) zero_arr[i] = 0;
    if (i == 0) {
        int or_hi = ei[1] | ei[3] | ei[5] | ei[7] | ei[9] | ei[11] | ei[13] | ei[15];
        *flag = (or_hi == 0) ? 1 : 0;
    }
}

__global__ __launch_bounds__(256) void position_bucket_kernel(
    const int* __restrict__ ei, const int* __restrict__ flag_p,
    int* __restrict__ cursor, int* __restrict__ csr_src, int E)
{
    int e = blockIdx.x * 256 + threadIdx.x;
    if (e >= E) return;
    int s, d;
    load_edge(ei, *flag_p, E, e, s, d);
    int slot = atomicAdd(&cursor[d], 1);
    if (slot < CAP) csr_src[(size_t)d * CAP + slot] = s;
}

__global__ __launch_bounds__(256) void gather_bucket_f32_kernel(
    const float* __restrict__ x, const int* __restrict__ ei,
    const int* __restrict__ flag_p, const int* __restrict__ cursor,
    const int* __restrict__ csr_src, float* __restrict__ agg, int N, int E)
{
    int node = blockIdx.x * 4 + (threadIdx.x >> 6);
    if (node >= N) return;
    int lane = threadIdx.x & 63;
    int half = lane >> 5;
    int col = lane & 31;
    int deg = cursor[node];

    const float4* x4 = reinterpret_cast<const float4*>(x);
    float4 a0 = make_float4(0.f, 0.f, 0.f, 0.f);
    float4 a1 = make_float4(0.f, 0.f, 0.f, 0.f);

    if (deg <= CAP) {
        int sv = (lane < deg) ? csr_src[(size_t)node * CAP + lane] : 0;
        int i = 0;
        for (; i + 3 < deg; i += 4) {
            int e0 = __shfl(sv, i + half);
            int e1 = __shfl(sv, i + 2 + half);
            float4 v0 = x4[(size_t)e0 * 32 + col];
            float4 v1 = x4[(size_t)e1 * 32 + col];
            a0.x += v0.x; a0.y += v0.y; a0.z += v0.z; a0.w += v0.w;
            a1.x += v1.x; a1.y += v1.y; a1.z += v1.z; a1.w += v1.w;
        }
        for (; i + 1 < deg; i += 2) {
            int e0 = __shfl(sv, i + half);
            float4 v0 = x4[(size_t)e0 * 32 + col];
            a0.x += v0.x; a0.y += v0.y; a0.z += v0.z; a0.w += v0.w;
        }
        if (i < deg) {
            int e0 = __shfl(sv, i);
            if (half == 0) {
                float4 v = x4[(size_t)e0 * 32 + col];
                a0.x += v.x; a0.y += v.y; a0.z += v.z; a0.w += v.w;
            }
        }
    } else {
        int is64 = *flag_p;
        for (int base = 0; base < E; base += 64) {
            int e = base + lane;
            int s = 0, d = -1;
            if (e < E) load_edge(ei, is64, E, e, s, d);
            unsigned long long m = __ballot(d == node);
            while (m) {
                int i = __ffsll((long long)m) - 1;
                m &= m - 1;
                int sb = __shfl(s, i);
                float4 v = x4[(size_t)sb * 32 + col];
                if (half == 0) { a0.x += v.x; a0.y += v.y; a0.z += v.z; a0.w += v.w; }
            }
        }
    }
    a0.x += a1.x; a0.y += a1.y; a0.z += a1.z; a0.w += a1.w;
    a0.x += __shfl_xor(a0.x, 32);
    a0.y += __shfl_xor(a0.y, 32);
    a0.z += __shfl_xor(a0.z, 32);
    a0.w += __shfl_xor(a0.w, 32);
    if (half == 0)
        reinterpret_cast<float4*>(agg)[(size_t)node * 32 + col] = a0;
}

__global__ __launch_bounds__(256) void scatter_kernel(
    const float* __restrict__ x, const int* __restrict__ ei,
    const int* __restrict__ flag_p, float* __restrict__ agg, int E)
{
    int tid = blockIdx.x * 256 + threadIdx.x;
    int e = tid >> 5;
    if (e >= E) return;
    int c = (tid & 31) << 2;
    int s, d;
    load_edge(ei, *flag_p, E, e, s, d);
    float4 v = *reinterpret_cast<const float4*>(x + (size_t)s * F + c);
    float* o = agg + (size_t)d * F + c;
    unsafeAtomicAdd(o + 0, v.x);
    unsafeAtomicAdd(o + 1, v.y);
    unsafeAtomicAdd(o + 2, v.z);
    unsafeAtomicAdd(o + 3, v.w);
}

// in-place fallback VALU GEMM: io = io @ W + bias
__global__ __launch_bounds__(256) void gemm_kernel(
    float* __restrict__ io, const float* __restrict__ W,
    const float* __restrict__ bias, int N)
{
    __shared__ float sA[TR * LDA];
    __shared__ float sW[KC * LDW];
    const int t = threadIdx.x;
    const int row0 = blockIdx.x * TR;
    const int g = t & 7;
    const int r = t >> 3;

    float acc[2][16];
    #pragma unroll
    for (int i = 0; i < 2; ++i)
        #pragma unroll
        for (int j = 0; j < 16; ++j) acc[i][j] = 0.0f;

    for (int kc = 0; kc < F; kc += KC) {
        #pragma unroll
        for (int u = 0; u < 2; ++u) {
            int idx = u * 256 + t;
            int row = idx >> 3;
            int k4 = (idx & 7) * 4;
            int grow = row0 + row;
            float4 v = (grow < N)
                ? *reinterpret_cast<const float4*>(io + (size_t)grow * F + kc + k4)
                : make_float4(0.f, 0.f, 0.f, 0.f);
            *reinterpret_cast<float4*>(&sA[row * LDA + k4]) = v;
        }
        #pragma unroll
        for (int u = 0; u < 4; ++u) {
            int idx = u * 256 + t;
            int kk = idx >> 5;
            int f4 = (idx & 31) * 4;
            float4 v = *reinterpret_cast<const float4*>(W + (size_t)(kc + kk) * F + f4);
            int chunk = f4 >> 4;
            int within = f4 & 15;
            *reinterpret_cast<float4*>(&sW[kk * LDW + chunk * 20 + within]) = v;
        }
        __syncthreads();

        #pragma unroll 8
        for (int kk = 0; kk < KC; ++kk) {
            const float* wp = &sW[kk * LDW + g * 20];
            const float4 w0 = *reinterpret_cast<const float4*>(wp + 0);
            const float4 w1 = *reinterpret_cast<const float4*>(wp + 4);
            const float4 w2 = *reinterpret_cast<const float4*>(wp + 8);
            const float4 w3 = *reinterpret_cast<const float4*>(wp + 12);
            #pragma unroll
            for (int i = 0; i < 2; ++i) {
                const float xv = sA[(r * 2 + i) * LDA + kk];
                acc[i][0]  += xv * w0.x;  acc[i][1]  += xv * w0.y;
                acc[i][2]  += xv * w0.z;  acc[i][3]  += xv * w0.w;
                acc[i][4]  += xv * w1.x;  acc[i][5]  += xv * w1.y;
                acc[i][6]  += xv * w1.z;  acc[i][7]  += xv * w1.w;
                acc[i][8]  += xv * w2.x;  acc[i][9]  += xv * w2.y;
                acc[i][10] += xv * w2.z;  acc[i][11] += xv * w2.w;
                acc[i][12] += xv * w3.x;  acc[i][13] += xv * w3.y;
                acc[i][14] += xv * w3.z;  acc[i][15] += xv * w3.w;
            }
        }
        __syncthreads();
    }

    float bv[16];
    #pragma unroll
    for (int j = 0; j < 16; ++j) bv[j] = bias[g * 16 + j];
    #pragma unroll
    for (int i = 0; i < 2; ++i) {
        int row = row0 + r * 2 + i;
        if (row < N) {
            float* o = io + (size_t)row * F + g * 16;
            #pragma unroll
            for (int j4 = 0; j4 < 4; ++j4) {
                float4 v;
                v.x = acc[i][j4 * 4 + 0] + bv[j4 * 4 + 0];
                v.y = acc[i][j4 * 4 + 1] + bv[j4 * 4 + 1];
                v.z = acc[i][j4 * 4 + 2] + bv[j4 * 4 + 2];
                v.w = acc[i][j4 * 4 + 3] + bv[j4 * 4 + 3];
                *reinterpret_cast<float4*>(o + j4 * 4) = v;
            }
        }
    }
}

extern "C" void kernel_launch(void* const* d_in, const int* in_sizes, int n_in,
                              void* d_out, int out_size, void* d_ws, size_t ws_size,
                              hipStream_t stream) {
    const float* x  = (const float*)d_in[0];
    const int*   ei = (const int*)d_in[1];
    const float* W2 = (const float*)d_in[5];
    const float* b2 = (const float*)d_in[6];
    float* out = (float*)d_out;

    const int N = in_sizes[0] / F;   // 50000
    const int E = in_sizes[2];       // 600000
    const int nblk = (N + 255) / 256;
    const int M = N * (F / 2);       // bf16-pair count for x
    const int eblk = (E + 255) / 256;

    int* ws = (int*)d_ws;
    // tier A: flag[16] i32, cursor[N] i32, csr16[N*CAP] u16, xh[M] u32,
    //         Wt[F*F] u16, aggbf[N*F/2] u32      (requires N <= 65536)
    size_t needA = (size_t)16 * 4 + (size_t)N * 4 + (size_t)N * CAP * 2
                 + (size_t)M * 4 + (size_t)F * F * 2 + (size_t)N * (F / 2) * 4;
    // tier B: flag[16], cursor[N], csr_src[N*CAP] i32
    size_t needB = (size_t)(16 + N + (size_t)N * CAP) * sizeof(int);

    if (ws_size >= needA && N <= 65536) {
        int* flag    = ws;
        int* cursor  = flag + 16;
        unsigned short* csr16 = (unsigned short*)(cursor + N);
        unsigned int*   xh    = (unsigned int*)(csr16 + (size_t)N * CAP);
        unsigned short* Wt    = (unsigned short*)(xh + M);
        unsigned int*   aggbf = (unsigned int*)(Wt + F * F);

        int pmax = M; if (N > pmax) pmax = N; if (F * F > pmax) pmax = F * F;
        prep_kernel<<<(pmax + 255) / 256, 256, 0, stream>>>(
            ei, x, W2, flag, cursor, xh, Wt, N, M);
        int pblk = ((E + 3) / 4 + 255) / 256;
        position4_kernel<<<pblk, 256, 0, stream>>>(ei, flag, cursor, csr16, E);
        gather_bucket_kernel<<<(N + 3) / 4, 256, 0, stream>>>(
            xh, ei, flag, cursor, csr16, aggbf, N, E);
        gemm_mfma_kernel<<<(N + 63) / 64, 256, 0, stream>>>(
            (const unsigned short*)aggbf, Wt, b2, out, N);
    } else if (ws_size >= needB) {
        int* flag    = ws;
        int* cursor  = flag + 16;
        int* csr_src = cursor + N;
        init_kernel<<<nblk, 256, 0, stream>>>(ei, flag, cursor, N);
        position_bucket_kernel<<<eblk, 256, 0, stream>>>(ei, flag, cursor, csr_src, E);
        gather_bucket_f32_kernel<<<(N + 3) / 4, 256, 0, stream>>>(
            x, ei, flag, cursor, csr_src, out, N, E);
        gemm_kernel<<<(N + TR - 1) / TR, 256, 0, stream>>>(out, W2, b2, N);
    } else {
        int* flag = ws;
        init_kernel<<<1, 64, 0, stream>>>(ei, flag, flag + 16, 0);
        hipMemsetAsync(out, 0, (size_t)N * F * sizeof(float), stream);
        scatter_kernel<<<(E * 32 + 255) / 256, 256, 0, stream>>>(x, ei, flag, out, E);
        gemm_kernel<<<(N + TR - 1) / TR, 256, 0, stream>>>(out, W2, b2, N);
    }
}